// Round 4
// baseline (397.432 us; speedup 1.0000x reference)
//
#include <hip/hip_runtime.h>

typedef unsigned int uint;
typedef unsigned short ushort;
typedef __bf16 v8bf __attribute__((ext_vector_type(8)));
typedef float v4f __attribute__((ext_vector_type(4)));

#define CCH 256
#define HH 336
#define WW 336
#define HWSZ (HH*WW)
#define NROI 2000
#define KDIM 12544       // 49*256
#define MPAD 2048
#define SPLITK 14
#define KSP (KDIM/SPLITK)   // 896

__device__ __forceinline__ ushort bf16r(float f) {
  uint u = __float_as_uint(f);
  u += 0x7fffu + ((u >> 16) & 1u);   // RTNE
  return (ushort)(u >> 16);
}
__device__ __forceinline__ uint packbf(float a, float b) {
  return (uint)bf16r(a) | ((uint)bf16r(b) << 16);
}

typedef const __attribute__((address_space(1))) uint* gas_t;
typedef __attribute__((address_space(3))) uint* las_t;
__device__ __forceinline__ void async16(const void* g, void* l) {
  __builtin_amdgcn_global_load_lds((gas_t)g, (las_t)l, 16, 0, 0);
}

// features [256][336][336] fp32 -> ft [hw][c] bf16, LDS-tiled.
__global__ __launch_bounds__(256) void k_transpose(const float* __restrict__ f,
                                                   uint* __restrict__ ftu) {
  __shared__ uint T[64 * 132];
  int tid = threadIdx.x;
  int hw0 = blockIdx.x * 64;
  int hwl = tid & 63;
  int cq = tid >> 6;              // 0..3
  int hw = hw0 + hwl;
#pragma unroll 4
  for (int it = 0; it < 32; ++it) {
    int c = it * 8 + cq * 2;
    float a = f[(size_t)c * HWSZ + hw];
    float b = f[(size_t)(c + 1) * HWSZ + hw];
    T[hwl * 132 + it * 4 + cq] = packbf(a, b);
  }
  __syncthreads();
  int co = tid & 31, r = tid >> 5;   // 8 rows per iter
#pragma unroll
  for (int i = 0; i < 8; ++i) {
    int hwr = i * 8 + r;
    uint4 v = *(const uint4*)&T[hwr * 132 + co * 4];
    *(uint4*)(ftu + (size_t)(hw0 + hwr) * 128 + co * 4) = v;
  }
}

// w1 [12544][256] fp32 (k = c*49+bin) -> w1t bf16 [n][k'] with k' = bin*256+c
__global__ __launch_bounds__(256) void k_w1perm(const float* __restrict__ w1,
                                                uint* __restrict__ w1t_u) {
  int bin = blockIdx.x % 49;
  int c0 = (blockIdx.x / 49) * 32;
  __shared__ ushort T[32][258];
  int n = threadIdx.x;
  for (int i = 0; i < 32; ++i)
    T[i][n] = bf16r(w1[(size_t)((c0 + i) * 49 + bin) * 256 + n]);
  __syncthreads();
  int cc = threadIdx.x & 15;
  int nb = threadIdx.x >> 4;
  for (int rep = 0; rep < 16; ++rep) {
    int nn = rep * 16 + nb;
    uint v = (uint)T[2 * cc][nn] | ((uint)T[2 * cc + 1][nn] << 16);
    w1t_u[(size_t)nn * (KDIM / 2) + bin * 128 + c0 / 2 + cc] = v;
  }
}

// w2 [256][256] -> w2t bf16 [n][k]
__global__ __launch_bounds__(256) void k_w2t(const float* __restrict__ w2,
                                             ushort* __restrict__ w2t) {
  int n = blockIdx.x, k = threadIdx.x;
  w2t[n * 256 + k] = bf16r(w2[k * 256 + n]);
}

// One 448-thread block per ROI; wave wv = bin-row. Per-bin x-segments with
// wave-uniform bounds -> unconditional adds (2 VALU/ch). Lanes: co = channel
// octet (uint4 16B), par = pixel parity. shfl_xor(32) cross-parity reduce.
#define UNPK8(u) do {                                        \
  a[0] += __uint_as_float((u).x << 16);                      \
  a[1] += __uint_as_float((u).x & 0xffff0000u);              \
  a[2] += __uint_as_float((u).y << 16);                      \
  a[3] += __uint_as_float((u).y & 0xffff0000u);              \
  a[4] += __uint_as_float((u).z << 16);                      \
  a[5] += __uint_as_float((u).z & 0xffff0000u);              \
  a[6] += __uint_as_float((u).w << 16);                      \
  a[7] += __uint_as_float((u).w & 0xffff0000u);              \
} while (0)

__global__ __launch_bounds__(448) void k_pool(const int* __restrict__ rois,
                                              const uint4* __restrict__ ft4,
                                              uint4* __restrict__ rf4) {
  int n = blockIdx.x;
  int wv = threadIdx.x >> 6;       // 0..6 bin-row
  int t = threadIdx.x & 63;
  int co = t & 31, par = t >> 5;
  int x1 = rois[n * 4 + 0], y1 = rois[n * 4 + 1];
  int x2 = rois[n * 4 + 2], y2 = rois[n * 4 + 3];
  int Lw = x2 - x1 + 1, Lh = y2 - y1 + 1;
  int ylo = y1 + (wv * Lh) / 7;
  int yhi = y1 + ((wv + 1) * Lh + 6) / 7;
  int rh = yhi - ylo;
  uint ob = (uint)n * 1568 + (uint)wv * 224 + co;
  for (int b = 0; b < 7; ++b) {
    int lo = x1 + (b * Lw) / 7;
    int hi = x1 + ((b + 1) * Lw + 6) / 7;
    float a[8];
#pragma unroll
    for (int j = 0; j < 8; ++j) a[j] = 0.f;
    for (int y = ylo; y < yhi; ++y) {
      const uint4* p = ft4 + (size_t)(y * WW + lo + par) * 32 + co;
      for (int x = lo + par; x < hi; x += 2) {
        uint4 u = *p; p += 64;
        UNPK8(u);
      }
    }
#pragma unroll
    for (int j = 0; j < 8; ++j) a[j] += __shfl_xor(a[j], 32, 64);
    if (t < 32) {
      float inv = 1.0f / (float)(rh * (hi - lo));
      uint4 o;
      o.x = packbf(a[0] * inv, a[1] * inv);
      o.y = packbf(a[2] * inv, a[3] * inv);
      o.z = packbf(a[4] * inv, a[5] * inv);
      o.w = packbf(a[6] * inv, a[7] * inv);
      rf4[ob + b * 32] = o;
    }
  }
}

// NT GEMM: A=rf [2048][12544], B=w1t [256][12544], tiles 128x64, split-K.
// 896 blocks (3.5/CU). 4 waves: wm=wv&1 (M 64), wn=wv>>1 (N 32).
__global__ __launch_bounds__(256) void k_gemm1(const ushort* __restrict__ A,
                                               const ushort* __restrict__ B,
                                               float* __restrict__ P) {
  __shared__ ushort As[128 * 64];
  __shared__ ushort Bs[64 * 64];
  int m0 = blockIdx.x * 128;
  int n0 = blockIdx.y * 64;
  int ks = blockIdx.z;
  int k0 = ks * KSP;
  int tid = threadIdx.x;
  int lane = tid & 63, wv = tid >> 6;
  int wm = wv & 1, wn = wv >> 1;
  int lm = lane & 15, quad = lane >> 4;
  int srow = tid >> 3, scol = (tid & 7) * 8;
  v4f acc[4][2];
#pragma unroll
  for (int i = 0; i < 4; ++i)
#pragma unroll
    for (int j = 0; j < 2; ++j) acc[i][j] = (v4f){0.f, 0.f, 0.f, 0.f};
  const ushort* Ab = A + (size_t)(m0 + srow) * KDIM + k0 + scol;
  const ushort* Bb = B + (size_t)(n0 + srow) * KDIM + k0 + scol;
  for (int kt = 0; kt < KSP / 64; ++kt) {
    __syncthreads();
#pragma unroll
    for (int r = 0; r < 4; ++r)
      async16(Ab + (size_t)(r * 32) * KDIM + kt * 64, &As[(srow + r * 32) * 64 + scol]);
#pragma unroll
    for (int r = 0; r < 2; ++r)
      async16(Bb + (size_t)(r * 32) * KDIM + kt * 64, &Bs[(srow + r * 32) * 64 + scol]);
    __syncthreads();
#pragma unroll
    for (int kk = 0; kk < 64; kk += 32) {
      v8bf a[4], b[2];
#pragma unroll
      for (int i = 0; i < 4; ++i)
        a[i] = *(const v8bf*)&As[(wm * 64 + i * 16 + lm) * 64 + kk + quad * 8];
#pragma unroll
      for (int j = 0; j < 2; ++j)
        b[j] = *(const v8bf*)&Bs[(wn * 32 + j * 16 + lm) * 64 + kk + quad * 8];
#pragma unroll
      for (int i = 0; i < 4; ++i)
#pragma unroll
        for (int j = 0; j < 2; ++j)
          acc[i][j] = __builtin_amdgcn_mfma_f32_16x16x32_bf16(a[i], b[j], acc[i][j], 0, 0, 0);
    }
  }
  float* Pb = P + (size_t)ks * MPAD * 256;
#pragma unroll
  for (int i = 0; i < 4; ++i)
#pragma unroll
    for (int j = 0; j < 2; ++j) {
      int row = m0 + wm * 64 + i * 16 + quad * 4;
      int col = n0 + wn * 32 + j * 16 + lm;
#pragma unroll
      for (int r = 0; r < 4; ++r)
        Pb[(size_t)(row + r) * 256 + col] = acc[i][j][r];
    }
}

// sum split-K partials + bias + relu -> h1 bf16 [2048][256]
__global__ __launch_bounds__(256) void k_reduce(const float* __restrict__ P,
                                                const float* __restrict__ b1,
                                                uint* __restrict__ h1u) {
  int idx = blockIdx.x * 256 + threadIdx.x;  // < 2048*128
  int m = idx >> 7, np = idx & 127;
  const float2* Pp = (const float2*)P;
  float2 s = {0.f, 0.f};
#pragma unroll
  for (int ks = 0; ks < SPLITK; ++ks) {
    float2 v = Pp[(size_t)(ks * MPAD + m) * 128 + np];
    s.x += v.x; s.y += v.y;
  }
  s.x += b1[2 * np]; s.y += b1[2 * np + 1];
  s.x = fmaxf(s.x, 0.f); s.y = fmaxf(s.y, 0.f);
  h1u[idx] = packbf(s.x, s.y);
}

// GEMM2 (64 rows x full N=256, K=256) + fused cls/reg heads
__global__ __launch_bounds__(256) void k_gemm2(const ushort* __restrict__ h1b,
                                               const ushort* __restrict__ w2t,
                                               const float* __restrict__ b2,
                                               const float* __restrict__ wcls,
                                               const float* __restrict__ bcls,
                                               const float* __restrict__ wreg,
                                               const float* __restrict__ breg,
                                               float* __restrict__ out) {
  __shared__ ushort As2[64 * 64];
  __shared__ ushort Bs2[256 * 64];
  __shared__ float Hs[64 * 257];
  int tid = threadIdx.x;
  int r0 = blockIdx.x * 64;
  int lane = tid & 63, wv = tid >> 6;
  int lm = lane & 15, quad = lane >> 4;
  int srow = tid >> 3, scol = (tid & 7) * 8;
  v4f acc[16];
#pragma unroll
  for (int j = 0; j < 16; ++j) acc[j] = (v4f){0.f, 0.f, 0.f, 0.f};
  for (int kt = 0; kt < 4; ++kt) {
    __syncthreads();
#pragma unroll
    for (int r = 0; r < 2; ++r)
      async16(h1b + (size_t)(r0 + srow + r * 32) * 256 + kt * 64 + scol,
              &As2[(srow + r * 32) * 64 + scol]);
#pragma unroll
    for (int r = 0; r < 8; ++r)
      async16(w2t + (size_t)(srow + r * 32) * 256 + kt * 64 + scol,
              &Bs2[(srow + r * 32) * 64 + scol]);
    __syncthreads();
#pragma unroll
    for (int kk = 0; kk < 64; kk += 32) {
      v8bf a = *(const v8bf*)&As2[(wv * 16 + lm) * 64 + kk + quad * 8];
#pragma unroll
      for (int j = 0; j < 16; ++j) {
        v8bf b = *(const v8bf*)&Bs2[(j * 16 + lm) * 64 + kk + quad * 8];
        acc[j] = __builtin_amdgcn_mfma_f32_16x16x32_bf16(a, b, acc[j], 0, 0, 0);
      }
    }
  }
#pragma unroll
  for (int j = 0; j < 16; ++j) {
    int nn = j * 16 + lm;
    float bb = b2[nn];
#pragma unroll
    for (int r = 0; r < 4; ++r) {
      int row = wv * 16 + quad * 4 + r;
      Hs[row * 257 + nn] = fmaxf(acc[j][r] + bb, 0.f);
    }
  }
  __syncthreads();
  for (int o = tid; o < 384; o += 256) {
    int hd = o >> 6, r = o & 63;
    int grow = r0 + r;
    float d = 0.f;
    if (hd < 2) {
      for (int k = 0; k < 256; ++k) d += Hs[r * 257 + k] * wcls[k * 2 + hd];
      d += bcls[hd];
      if (grow < NROI) out[grow * 2 + hd] = d;
    } else {
      int h4 = hd - 2;
      for (int k = 0; k < 256; ++k) d += Hs[r * 257 + k] * wreg[k * 4 + h4];
      d += breg[h4];
      if (grow < NROI) out[4000 + grow * 4 + h4] = d;
    }
  }
}

extern "C" void kernel_launch(void* const* d_in, const int* in_sizes, int n_in,
                              void* d_out, int out_size, void* d_ws, size_t ws_size,
                              hipStream_t stream) {
  const float* features = (const float*)d_in[0];
  const int* rois = (const int*)d_in[1];
  const float* w1 = (const float*)d_in[2];
  const float* b1 = (const float*)d_in[3];
  const float* w2 = (const float*)d_in[4];
  const float* b2 = (const float*)d_in[5];
  const float* wcls = (const float*)d_in[6];
  const float* bcls = (const float*)d_in[7];
  const float* wreg = (const float*)d_in[8];
  const float* breg = (const float*)d_in[9];
  char* ws = (char*)d_ws;
  ushort* ft  = (ushort*)(ws + 0);          // 57,802,752 B
  ushort* w1t = (ushort*)(ws + 57802752);   //  6,422,528 B
  ushort* w2t = (ushort*)(ws + 64225280);   //    131,072 B
  ushort* rf  = (ushort*)(ws + 64356352);   // 51,380,224 B (2048 rows)
  float*  P   = (float*)(ws + 115736576);   // 29,360,128 B
  ushort* h1b = (ushort*)(ws + 145096704);  //  1,048,576 B
  float* out = (float*)d_out;

  hipLaunchKernelGGL(k_transpose, dim3(HWSZ / 64), dim3(256), 0, stream,
                     features, (uint*)ft);
  hipLaunchKernelGGL(k_w1perm, dim3(392), dim3(256), 0, stream, w1, (uint*)w1t);
  hipLaunchKernelGGL(k_w2t, dim3(256), dim3(256), 0, stream, w2, w2t);
  hipLaunchKernelGGL(k_pool, dim3(NROI), dim3(448), 0, stream, rois,
                     (const uint4*)ft, (uint4*)rf);
  hipLaunchKernelGGL(k_gemm1, dim3(16, 4, SPLITK), dim3(256), 0, stream, rf, w1t, P);
  hipLaunchKernelGGL(k_reduce, dim3(1024), dim3(256), 0, stream, P, b1, (uint*)h1b);
  hipLaunchKernelGGL(k_gemm2, dim3(32), dim3(256), 0, stream, h1b, w2t, b2, wcls, bcls, wreg, breg, out);
}

// Round 5
// 370.366 us; speedup vs baseline: 1.0731x; 1.0731x over previous
//
#include <hip/hip_runtime.h>

typedef unsigned int uint;
typedef unsigned short ushort;
typedef __bf16 v8bf __attribute__((ext_vector_type(8)));
typedef float v4f __attribute__((ext_vector_type(4)));

#define CCH 256
#define HH 336
#define WW 336
#define HWSZ (HH*WW)
#define NROI 2000
#define KDIM 12544       // 49*256
#define MPAD 2048
#define SPLITK 14
#define KSP (KDIM/SPLITK)   // 896

__device__ __forceinline__ ushort bf16r(float f) {
  uint u = __float_as_uint(f);
  u += 0x7fffu + ((u >> 16) & 1u);   // RTNE
  return (ushort)(u >> 16);
}
__device__ __forceinline__ uint packbf(float a, float b) {
  return (uint)bf16r(a) | ((uint)bf16r(b) << 16);
}

typedef const __attribute__((address_space(1))) uint* gas_t;
typedef __attribute__((address_space(3))) uint* las_t;
__device__ __forceinline__ void async16(const void* g, void* l) {
  __builtin_amdgcn_global_load_lds((gas_t)g, (las_t)l, 16, 0, 0);
}

// features [256][336][336] fp32 -> ft [hw][c] bf16, LDS-tiled.
__global__ __launch_bounds__(256) void k_transpose(const float* __restrict__ f,
                                                   uint* __restrict__ ftu) {
  __shared__ uint T[64 * 132];
  int tid = threadIdx.x;
  int hw0 = blockIdx.x * 64;
  int hwl = tid & 63;
  int cq = tid >> 6;              // 0..3
  int hw = hw0 + hwl;
#pragma unroll 4
  for (int it = 0; it < 32; ++it) {
    int c = it * 8 + cq * 2;
    float a = f[(size_t)c * HWSZ + hw];
    float b = f[(size_t)(c + 1) * HWSZ + hw];
    T[hwl * 132 + it * 4 + cq] = packbf(a, b);
  }
  __syncthreads();
  int co = tid & 31, r = tid >> 5;   // 8 rows per iter
#pragma unroll
  for (int i = 0; i < 8; ++i) {
    int hwr = i * 8 + r;
    uint4 v = *(const uint4*)&T[hwr * 132 + co * 4];
    *(uint4*)(ftu + (size_t)(hw0 + hwr) * 128 + co * 4) = v;
  }
}

// w1 [12544][256] fp32 (k = c*49+bin) -> w1t bf16 [n][k'] with k' = bin*256+c
__global__ __launch_bounds__(256) void k_w1perm(const float* __restrict__ w1,
                                                uint* __restrict__ w1t_u) {
  int bin = blockIdx.x % 49;
  int c0 = (blockIdx.x / 49) * 32;
  __shared__ ushort T[32][258];
  int n = threadIdx.x;
  for (int i = 0; i < 32; ++i)
    T[i][n] = bf16r(w1[(size_t)((c0 + i) * 49 + bin) * 256 + n]);
  __syncthreads();
  int cc = threadIdx.x & 15;
  int nb = threadIdx.x >> 4;
  for (int rep = 0; rep < 16; ++rep) {
    int nn = rep * 16 + nb;
    uint v = (uint)T[2 * cc][nn] | ((uint)T[2 * cc + 1][nn] << 16);
    w1t_u[(size_t)nn * (KDIM / 2) + bin * 128 + c0 / 2 + cc] = v;
  }
}

// w2 [256][256] -> w2t bf16 [n][k]
__global__ __launch_bounds__(256) void k_w2t(const float* __restrict__ w2,
                                             ushort* __restrict__ w2t) {
  int n = blockIdx.x, k = threadIdx.x;
  w2t[n * 256 + k] = bf16r(w2[k * 256 + n]);
}

// Counting-sort ROIs by spatial tile (8x8 grid of 42px) -> perm.
__global__ __launch_bounds__(256) void k_sort(const int* __restrict__ rois,
                                              int* __restrict__ perm) {
  __shared__ int hist[64];
  __shared__ int keys[NROI];
  int tid = threadIdx.x;
  if (tid < 64) hist[tid] = 0;
  __syncthreads();
  for (int i = tid; i < NROI; i += 256) {
    int x1 = rois[i * 4 + 0], y1 = rois[i * 4 + 1];
    int x2 = rois[i * 4 + 2], y2 = rois[i * 4 + 3];
    int cx = (x1 + x2) >> 1, cy = (y1 + y2) >> 1;
    int k = (cy / 42) * 8 + (cx / 42);
    keys[i] = k;
    atomicAdd(&hist[k], 1);
  }
  __syncthreads();
  if (tid == 0) {
    int s = 0;
    for (int b = 0; b < 64; ++b) { int c = hist[b]; hist[b] = s; s += c; }
  }
  __syncthreads();
  for (int i = tid; i < NROI; i += 256) {
    int pos = atomicAdd(&hist[keys[i]], 1);
    perm[pos] = i;
  }
}

// One 448-thread block per ROI; wave wv = bin-row. Per-bin x-segments with
// wave-uniform bounds. XCD-chunked spatially-sorted ROI assignment: XCD j
// (blockIdx%8) gets sorted slots [j*250, (j+1)*250) for L2 reuse.
#define UNPK8(u) do {                                        \
  a[0] += __uint_as_float((u).x << 16);                      \
  a[1] += __uint_as_float((u).x & 0xffff0000u);              \
  a[2] += __uint_as_float((u).y << 16);                      \
  a[3] += __uint_as_float((u).y & 0xffff0000u);              \
  a[4] += __uint_as_float((u).z << 16);                      \
  a[5] += __uint_as_float((u).z & 0xffff0000u);              \
  a[6] += __uint_as_float((u).w << 16);                      \
  a[7] += __uint_as_float((u).w & 0xffff0000u);              \
} while (0)

__global__ __launch_bounds__(448) void k_pool(const int* __restrict__ rois,
                                              const int* __restrict__ perm,
                                              const uint4* __restrict__ ft4,
                                              uint4* __restrict__ rf4) {
  int slot = (blockIdx.x & 7) * 250 + (blockIdx.x >> 3);
  int n = perm[slot];
  int wv = threadIdx.x >> 6;       // 0..6 bin-row
  int t = threadIdx.x & 63;
  int co = t & 31, par = t >> 5;
  int x1 = rois[n * 4 + 0], y1 = rois[n * 4 + 1];
  int x2 = rois[n * 4 + 2], y2 = rois[n * 4 + 3];
  int Lw = x2 - x1 + 1, Lh = y2 - y1 + 1;
  int ylo = y1 + (wv * Lh) / 7;
  int yhi = y1 + ((wv + 1) * Lh + 6) / 7;
  int rh = yhi - ylo;
  uint ob = (uint)n * 1568 + (uint)wv * 224 + co;
  for (int b = 0; b < 7; ++b) {
    int lo = x1 + (b * Lw) / 7;
    int hi = x1 + ((b + 1) * Lw + 6) / 7;
    float a[8];
#pragma unroll
    for (int j = 0; j < 8; ++j) a[j] = 0.f;
    for (int y = ylo; y < yhi; ++y) {
      const uint4* p = ft4 + (size_t)(y * WW + lo + par) * 32 + co;
      for (int x = lo + par; x < hi; x += 2) {
        uint4 u = *p; p += 64;
        UNPK8(u);
      }
    }
#pragma unroll
    for (int j = 0; j < 8; ++j) a[j] += __shfl_xor(a[j], 32, 64);
    if (t < 32) {
      float inv = 1.0f / (float)(rh * (hi - lo));
      uint4 o;
      o.x = packbf(a[0] * inv, a[1] * inv);
      o.y = packbf(a[2] * inv, a[3] * inv);
      o.z = packbf(a[4] * inv, a[5] * inv);
      o.w = packbf(a[6] * inv, a[7] * inv);
      rf4[ob + b * 32] = o;
    }
  }
}

// NT GEMM: A=rf [2048][12544], B=w1t [256][12544], tiles 128x64, split-K.
__global__ __launch_bounds__(256) void k_gemm1(const ushort* __restrict__ A,
                                               const ushort* __restrict__ B,
                                               float* __restrict__ P) {
  __shared__ ushort As[128 * 64];
  __shared__ ushort Bs[64 * 64];
  int m0 = blockIdx.x * 128;
  int n0 = blockIdx.y * 64;
  int ks = blockIdx.z;
  int k0 = ks * KSP;
  int tid = threadIdx.x;
  int lane = tid & 63, wv = tid >> 6;
  int wm = wv & 1, wn = wv >> 1;
  int lm = lane & 15, quad = lane >> 4;
  int srow = tid >> 3, scol = (tid & 7) * 8;
  v4f acc[4][2];
#pragma unroll
  for (int i = 0; i < 4; ++i)
#pragma unroll
    for (int j = 0; j < 2; ++j) acc[i][j] = (v4f){0.f, 0.f, 0.f, 0.f};
  const ushort* Ab = A + (size_t)(m0 + srow) * KDIM + k0 + scol;
  const ushort* Bb = B + (size_t)(n0 + srow) * KDIM + k0 + scol;
  for (int kt = 0; kt < KSP / 64; ++kt) {
    __syncthreads();
#pragma unroll
    for (int r = 0; r < 4; ++r)
      async16(Ab + (size_t)(r * 32) * KDIM + kt * 64, &As[(srow + r * 32) * 64 + scol]);
#pragma unroll
    for (int r = 0; r < 2; ++r)
      async16(Bb + (size_t)(r * 32) * KDIM + kt * 64, &Bs[(srow + r * 32) * 64 + scol]);
    __syncthreads();
#pragma unroll
    for (int kk = 0; kk < 64; kk += 32) {
      v8bf a[4], b[2];
#pragma unroll
      for (int i = 0; i < 4; ++i)
        a[i] = *(const v8bf*)&As[(wm * 64 + i * 16 + lm) * 64 + kk + quad * 8];
#pragma unroll
      for (int j = 0; j < 2; ++j)
        b[j] = *(const v8bf*)&Bs[(wn * 32 + j * 16 + lm) * 64 + kk + quad * 8];
#pragma unroll
      for (int i = 0; i < 4; ++i)
#pragma unroll
        for (int j = 0; j < 2; ++j)
          acc[i][j] = __builtin_amdgcn_mfma_f32_16x16x32_bf16(a[i], b[j], acc[i][j], 0, 0, 0);
    }
  }
  float* Pb = P + (size_t)ks * MPAD * 256;
#pragma unroll
  for (int i = 0; i < 4; ++i)
#pragma unroll
    for (int j = 0; j < 2; ++j) {
      int row = m0 + wm * 64 + i * 16 + quad * 4;
      int col = n0 + wn * 32 + j * 16 + lm;
#pragma unroll
      for (int r = 0; r < 4; ++r)
        Pb[(size_t)(row + r) * 256 + col] = acc[i][j][r];
    }
}

// sum split-K partials + bias + relu -> h1 bf16 [2048][256]
__global__ __launch_bounds__(256) void k_reduce(const float* __restrict__ P,
                                                const float* __restrict__ b1,
                                                uint* __restrict__ h1u) {
  int idx = blockIdx.x * 256 + threadIdx.x;  // < 2048*128
  int m = idx >> 7, np = idx & 127;
  const float2* Pp = (const float2*)P;
  float2 s = {0.f, 0.f};
#pragma unroll
  for (int ks = 0; ks < SPLITK; ++ks) {
    float2 v = Pp[(size_t)(ks * MPAD + m) * 128 + np];
    s.x += v.x; s.y += v.y;
  }
  s.x += b1[2 * np]; s.y += b1[2 * np + 1];
  s.x = fmaxf(s.x, 0.f); s.y = fmaxf(s.y, 0.f);
  h1u[idx] = packbf(s.x, s.y);
}

// GEMM2 (64 rows x full N=256, K=256) + fused cls/reg heads
__global__ __launch_bounds__(256) void k_gemm2(const ushort* __restrict__ h1b,
                                               const ushort* __restrict__ w2t,
                                               const float* __restrict__ b2,
                                               const float* __restrict__ wcls,
                                               const float* __restrict__ bcls,
                                               const float* __restrict__ wreg,
                                               const float* __restrict__ breg,
                                               float* __restrict__ out) {
  __shared__ ushort As2[64 * 64];
  __shared__ ushort Bs2[256 * 64];
  __shared__ float Hs[64 * 257];
  int tid = threadIdx.x;
  int r0 = blockIdx.x * 64;
  int lane = tid & 63, wv = tid >> 6;
  int lm = lane & 15, quad = lane >> 4;
  int srow = tid >> 3, scol = (tid & 7) * 8;
  v4f acc[16];
#pragma unroll
  for (int j = 0; j < 16; ++j) acc[j] = (v4f){0.f, 0.f, 0.f, 0.f};
  for (int kt = 0; kt < 4; ++kt) {
    __syncthreads();
#pragma unroll
    for (int r = 0; r < 2; ++r)
      async16(h1b + (size_t)(r0 + srow + r * 32) * 256 + kt * 64 + scol,
              &As2[(srow + r * 32) * 64 + scol]);
#pragma unroll
    for (int r = 0; r < 8; ++r)
      async16(w2t + (size_t)(srow + r * 32) * 256 + kt * 64 + scol,
              &Bs2[(srow + r * 32) * 64 + scol]);
    __syncthreads();
#pragma unroll
    for (int kk = 0; kk < 64; kk += 32) {
      v8bf a = *(const v8bf*)&As2[(wv * 16 + lm) * 64 + kk + quad * 8];
#pragma unroll
      for (int j = 0; j < 16; ++j) {
        v8bf b = *(const v8bf*)&Bs2[(j * 16 + lm) * 64 + kk + quad * 8];
        acc[j] = __builtin_amdgcn_mfma_f32_16x16x32_bf16(a, b, acc[j], 0, 0, 0);
      }
    }
  }
#pragma unroll
  for (int j = 0; j < 16; ++j) {
    int nn = j * 16 + lm;
    float bb = b2[nn];
#pragma unroll
    for (int r = 0; r < 4; ++r) {
      int row = wv * 16 + quad * 4 + r;
      Hs[row * 257 + nn] = fmaxf(acc[j][r] + bb, 0.f);
    }
  }
  __syncthreads();
  for (int o = tid; o < 384; o += 256) {
    int hd = o >> 6, r = o & 63;
    int grow = r0 + r;
    float d = 0.f;
    if (hd < 2) {
      for (int k = 0; k < 256; ++k) d += Hs[r * 257 + k] * wcls[k * 2 + hd];
      d += bcls[hd];
      if (grow < NROI) out[grow * 2 + hd] = d;
    } else {
      int h4 = hd - 2;
      for (int k = 0; k < 256; ++k) d += Hs[r * 257 + k] * wreg[k * 4 + h4];
      d += breg[h4];
      if (grow < NROI) out[4000 + grow * 4 + h4] = d;
    }
  }
}

extern "C" void kernel_launch(void* const* d_in, const int* in_sizes, int n_in,
                              void* d_out, int out_size, void* d_ws, size_t ws_size,
                              hipStream_t stream) {
  const float* features = (const float*)d_in[0];
  const int* rois = (const int*)d_in[1];
  const float* w1 = (const float*)d_in[2];
  const float* b1 = (const float*)d_in[3];
  const float* w2 = (const float*)d_in[4];
  const float* b2 = (const float*)d_in[5];
  const float* wcls = (const float*)d_in[6];
  const float* bcls = (const float*)d_in[7];
  const float* wreg = (const float*)d_in[8];
  const float* breg = (const float*)d_in[9];
  char* ws = (char*)d_ws;
  ushort* ft  = (ushort*)(ws + 0);          // 57,802,752 B
  ushort* w1t = (ushort*)(ws + 57802752);   //  6,422,528 B
  ushort* w2t = (ushort*)(ws + 64225280);   //    131,072 B
  ushort* rf  = (ushort*)(ws + 64356352);   // 51,380,224 B (2048 rows; rows
                                            // 2000+ are GEMM padding)
  // perm lives in rf's padding rows (read by gemm1 as harmless tiny bf16)
  int*    perm = (int*)(ws + 64356352 + (size_t)NROI * KDIM * 2);
  float*  P   = (float*)(ws + 115736576);   // 29,360,128 B
  ushort* h1b = (ushort*)(ws + 145096704);  //  1,048,576 B
  float* out = (float*)d_out;

  hipLaunchKernelGGL(k_transpose, dim3(HWSZ / 64), dim3(256), 0, stream,
                     features, (uint*)ft);
  hipLaunchKernelGGL(k_w1perm, dim3(392), dim3(256), 0, stream, w1, (uint*)w1t);
  hipLaunchKernelGGL(k_w2t, dim3(256), dim3(256), 0, stream, w2, w2t);
  hipLaunchKernelGGL(k_sort, dim3(1), dim3(256), 0, stream, rois, perm);
  hipLaunchKernelGGL(k_pool, dim3(NROI), dim3(448), 0, stream, rois, perm,
                     (const uint4*)ft, (uint4*)rf);
  hipLaunchKernelGGL(k_gemm1, dim3(16, 4, SPLITK), dim3(256), 0, stream, rf, w1t, P);
  hipLaunchKernelGGL(k_reduce, dim3(1024), dim3(256), 0, stream, P, b1, (uint*)h1b);
  hipLaunchKernelGGL(k_gemm2, dim3(32), dim3(256), 0, stream, h1b, w2t, b2, wcls, bcls, wreg, breg, out);
}

// Round 7
// 354.047 us; speedup vs baseline: 1.1225x; 1.0461x over previous
//
#include <hip/hip_runtime.h>

typedef unsigned int uint;
typedef unsigned short ushort;
typedef __bf16 v8bf __attribute__((ext_vector_type(8)));
typedef float v4f __attribute__((ext_vector_type(4)));

#define CCH 256
#define HH 336
#define WW 336
#define HWSZ (HH*WW)
#define NROI 2000
#define KDIM 12544       // 49*256
#define MPAD 2048
#define SPLITK 14
#define KSP (KDIM/SPLITK)   // 896

__device__ __forceinline__ ushort bf16r(float f) {
  uint u = __float_as_uint(f);
  u += 0x7fffu + ((u >> 16) & 1u);   // RTNE
  return (ushort)(u >> 16);
}
__device__ __forceinline__ uint packbf(float a, float b) {
  return (uint)bf16r(a) | ((uint)bf16r(b) << 16);
}

typedef const __attribute__((address_space(1))) uint* gas_t;
typedef __attribute__((address_space(3))) uint* las_t;
__device__ __forceinline__ void async16(const void* g, void* l) {
  __builtin_amdgcn_global_load_lds((gas_t)g, (las_t)l, 16, 0, 0);
}

// features [256][336][336] fp32 -> ft [hw][c] bf16, LDS-tiled.
__global__ __launch_bounds__(256) void k_transpose(const float* __restrict__ f,
                                                   uint* __restrict__ ftu) {
  __shared__ uint T[64 * 132];
  int tid = threadIdx.x;
  int hw0 = blockIdx.x * 64;
  int hwl = tid & 63;
  int cq = tid >> 6;              // 0..3
  int hw = hw0 + hwl;
#pragma unroll 4
  for (int it = 0; it < 32; ++it) {
    int c = it * 8 + cq * 2;
    float a = f[(size_t)c * HWSZ + hw];
    float b = f[(size_t)(c + 1) * HWSZ + hw];
    T[hwl * 132 + it * 4 + cq] = packbf(a, b);
  }
  __syncthreads();
  int co = tid & 31, r = tid >> 5;   // 8 rows per iter
#pragma unroll
  for (int i = 0; i < 8; ++i) {
    int hwr = i * 8 + r;
    uint4 v = *(const uint4*)&T[hwr * 132 + co * 4];
    *(uint4*)(ftu + (size_t)(hw0 + hwr) * 128 + co * 4) = v;
  }
}

// w1 [12544][256] fp32 (k = c*49+bin) -> w1t bf16 [n][k'] with k' = bin*256+c
__global__ __launch_bounds__(256) void k_w1perm(const float* __restrict__ w1,
                                                uint* __restrict__ w1t_u) {
  int bin = blockIdx.x % 49;
  int c0 = (blockIdx.x / 49) * 32;
  __shared__ ushort T[32][258];
  int n = threadIdx.x;
  for (int i = 0; i < 32; ++i)
    T[i][n] = bf16r(w1[(size_t)((c0 + i) * 49 + bin) * 256 + n]);
  __syncthreads();
  int cc = threadIdx.x & 15;
  int nb = threadIdx.x >> 4;
  for (int rep = 0; rep < 16; ++rep) {
    int nn = rep * 16 + nb;
    uint v = (uint)T[2 * cc][nn] | ((uint)T[2 * cc + 1][nn] << 16);
    w1t_u[(size_t)nn * (KDIM / 2) + bin * 128 + c0 / 2 + cc] = v;
  }
}

// w2 [256][256] -> w2t bf16 [n][k]
__global__ __launch_bounds__(256) void k_w2t(const float* __restrict__ w2,
                                             ushort* __restrict__ w2t) {
  int n = blockIdx.x, k = threadIdx.x;
  w2t[n * 256 + k] = bf16r(w2[k * 256 + n]);
}

// Counting-sort ROIs by spatial tile (8x8 grid of 42px) -> perm.
__global__ __launch_bounds__(256) void k_sort(const int* __restrict__ rois,
                                              int* __restrict__ perm) {
  __shared__ int hist[64];
  __shared__ int keys[NROI];
  int tid = threadIdx.x;
  if (tid < 64) hist[tid] = 0;
  __syncthreads();
  for (int i = tid; i < NROI; i += 256) {
    int x1 = rois[i * 4 + 0], y1 = rois[i * 4 + 1];
    int x2 = rois[i * 4 + 2], y2 = rois[i * 4 + 3];
    int cx = (x1 + x2) >> 1, cy = (y1 + y2) >> 1;
    int k = (cy / 42) * 8 + (cx / 42);
    keys[i] = k;
    atomicAdd(&hist[k], 1);
  }
  __syncthreads();
  if (tid == 0) {
    int s = 0;
    for (int b = 0; b < 64; ++b) { int c = hist[b]; hist[b] = s; s += c; }
  }
  __syncthreads();
  for (int i = tid; i < NROI; i += 256) {
    int pos = atomicAdd(&hist[keys[i]], 1);
    perm[pos] = i;
  }
}

// grid (NROI, 7): one wave per (sorted ROI, bin-row). XCD-chunked ROI
// assignment (blockIdx.x%8 -> XCD) for L2 reuse. Per-bin wave-uniform x
// segments; lanes: co=channel octet (uint4), par=pixel parity. 2-stream
// unroll: lane-consecutive pixels are 64 uint4 apart (2 px * 32 uint4),
// so stream 2 is p[64] and p advances 128 per x+=4.  (R5 bug: p[128]/+=256
// skipped x+2 and read x+4 out-of-bin.)
#define UNPK8(A, u) do {                                     \
  A[0] += __uint_as_float((u).x << 16);                      \
  A[1] += __uint_as_float((u).x & 0xffff0000u);              \
  A[2] += __uint_as_float((u).y << 16);                      \
  A[3] += __uint_as_float((u).y & 0xffff0000u);              \
  A[4] += __uint_as_float((u).z << 16);                      \
  A[5] += __uint_as_float((u).z & 0xffff0000u);              \
  A[6] += __uint_as_float((u).w << 16);                      \
  A[7] += __uint_as_float((u).w & 0xffff0000u);              \
} while (0)

__global__ __launch_bounds__(64) void k_pool(const int* __restrict__ rois,
                                             const int* __restrict__ perm,
                                             const uint4* __restrict__ ft4,
                                             uint4* __restrict__ rf4) {
  int bx = blockIdx.x;
  int slot = (bx & 7) * 250 + (bx >> 3);
  int n = perm[slot];
  int wv = blockIdx.y;             // 0..6 bin-row
  int t = threadIdx.x;
  int co = t & 31, par = t >> 5;
  int x1 = rois[n * 4 + 0], y1 = rois[n * 4 + 1];
  int x2 = rois[n * 4 + 2], y2 = rois[n * 4 + 3];
  int Lw = x2 - x1 + 1, Lh = y2 - y1 + 1;
  int ylo = y1 + (wv * Lh) / 7;
  int yhi = y1 + ((wv + 1) * Lh + 6) / 7;
  int rh = yhi - ylo;
  uint ob = (uint)n * 1568 + (uint)wv * 224 + co;
  for (int b = 0; b < 7; ++b) {
    int lo = x1 + (b * Lw) / 7;
    int hi = x1 + ((b + 1) * Lw + 6) / 7;
    float a[8], c[8];
#pragma unroll
    for (int j = 0; j < 8; ++j) { a[j] = 0.f; c[j] = 0.f; }
    for (int y = ylo; y < yhi; ++y) {
      const uint4* p = ft4 + (size_t)(y * WW + lo + par) * 32 + co;
      int x = lo + par;
      for (; x + 2 < hi; x += 4) {
        uint4 u0 = p[0], u1 = p[64];
        p += 128;
        UNPK8(a, u0);
        UNPK8(c, u1);
      }
      for (; x < hi; x += 2) {
        uint4 u = p[0];
        p += 64;
        UNPK8(a, u);
      }
    }
#pragma unroll
    for (int j = 0; j < 8; ++j) a[j] += c[j];
#pragma unroll
    for (int j = 0; j < 8; ++j) a[j] += __shfl_xor(a[j], 32, 64);
    if (t < 32) {
      float inv = 1.0f / (float)(rh * (hi - lo));
      uint4 o;
      o.x = packbf(a[0] * inv, a[1] * inv);
      o.y = packbf(a[2] * inv, a[3] * inv);
      o.z = packbf(a[4] * inv, a[5] * inv);
      o.w = packbf(a[6] * inv, a[7] * inv);
      rf4[ob + b * 32] = o;
    }
  }
}

// NT GEMM: A=rf [2048][12544], B=w1t [256][12544], 128x128 tile (m97
// structure: 32 MFMA/barrier), split-K -> P [14][2048][256] fp32
__global__ __launch_bounds__(256) void k_gemm1(const ushort* __restrict__ A,
                                               const ushort* __restrict__ B,
                                               float* __restrict__ P) {
  __shared__ ushort As[128 * 64];
  __shared__ ushort Bs[128 * 64];
  int m0 = blockIdx.x * 128;
  int n0 = blockIdx.y * 128;
  int ks = blockIdx.z;
  int k0 = ks * KSP;
  int tid = threadIdx.x;
  int lane = tid & 63, wv = tid >> 6;
  int wm = wv >> 1, wn = wv & 1;
  int lm = lane & 15, quad = lane >> 4;
  int srow = tid >> 3, scol = (tid & 7) * 8;
  v4f acc[4][4];
#pragma unroll
  for (int i = 0; i < 4; ++i)
#pragma unroll
    for (int j = 0; j < 4; ++j) acc[i][j] = (v4f){0.f, 0.f, 0.f, 0.f};
  const ushort* Ab = A + (size_t)(m0 + srow) * KDIM + k0 + scol;
  const ushort* Bb = B + (size_t)(n0 + srow) * KDIM + k0 + scol;
  for (int kt = 0; kt < KSP / 64; ++kt) {
    __syncthreads();
#pragma unroll
    for (int r = 0; r < 4; ++r)
      async16(Ab + (size_t)(r * 32) * KDIM + kt * 64, &As[(srow + r * 32) * 64 + scol]);
#pragma unroll
    for (int r = 0; r < 4; ++r)
      async16(Bb + (size_t)(r * 32) * KDIM + kt * 64, &Bs[(srow + r * 32) * 64 + scol]);
    __syncthreads();
#pragma unroll
    for (int kk = 0; kk < 64; kk += 32) {
      v8bf a[4], b[4];
#pragma unroll
      for (int i = 0; i < 4; ++i)
        a[i] = *(const v8bf*)&As[(wm * 64 + i * 16 + lm) * 64 + kk + quad * 8];
#pragma unroll
      for (int j = 0; j < 4; ++j)
        b[j] = *(const v8bf*)&Bs[(wn * 64 + j * 16 + lm) * 64 + kk + quad * 8];
#pragma unroll
      for (int i = 0; i < 4; ++i)
#pragma unroll
        for (int j = 0; j < 4; ++j)
          acc[i][j] = __builtin_amdgcn_mfma_f32_16x16x32_bf16(a[i], b[j], acc[i][j], 0, 0, 0);
    }
  }
  float* Pb = P + (size_t)ks * MPAD * 256;
#pragma unroll
  for (int i = 0; i < 4; ++i)
#pragma unroll
    for (int j = 0; j < 4; ++j) {
      int row = m0 + wm * 64 + i * 16 + quad * 4;
      int col = n0 + wn * 64 + j * 16 + lm;
#pragma unroll
      for (int r = 0; r < 4; ++r)
        Pb[(size_t)(row + r) * 256 + col] = acc[i][j][r];
    }
}

// sum split-K partials + bias + relu -> h1 bf16 [2048][256]
__global__ __launch_bounds__(256) void k_reduce(const float* __restrict__ P,
                                                const float* __restrict__ b1,
                                                uint* __restrict__ h1u) {
  int idx = blockIdx.x * 256 + threadIdx.x;  // < 2048*128
  int m = idx >> 7, np = idx & 127;
  const float2* Pp = (const float2*)P;
  float2 s = {0.f, 0.f};
#pragma unroll
  for (int ks = 0; ks < SPLITK; ++ks) {
    float2 v = Pp[(size_t)(ks * MPAD + m) * 128 + np];
    s.x += v.x; s.y += v.y;
  }
  s.x += b1[2 * np]; s.y += b1[2 * np + 1];
  s.x = fmaxf(s.x, 0.f); s.y = fmaxf(s.y, 0.f);
  h1u[idx] = packbf(s.x, s.y);
}

// GEMM2 (64 rows x full N=256, K=256) + fused cls/reg heads
__global__ __launch_bounds__(256) void k_gemm2(const ushort* __restrict__ h1b,
                                               const ushort* __restrict__ w2t,
                                               const float* __restrict__ b2,
                                               const float* __restrict__ wcls,
                                               const float* __restrict__ bcls,
                                               const float* __restrict__ wreg,
                                               const float* __restrict__ breg,
                                               float* __restrict__ out) {
  __shared__ ushort As2[64 * 64];
  __shared__ ushort Bs2[256 * 64];
  __shared__ float Hs[64 * 257];
  int tid = threadIdx.x;
  int r0 = blockIdx.x * 64;
  int lane = tid & 63, wv = tid >> 6;
  int lm = lane & 15, quad = lane >> 4;
  int srow = tid >> 3, scol = (tid & 7) * 8;
  v4f acc[16];
#pragma unroll
  for (int j = 0; j < 16; ++j) acc[j] = (v4f){0.f, 0.f, 0.f, 0.f};
  for (int kt = 0; kt < 4; ++kt) {
    __syncthreads();
#pragma unroll
    for (int r = 0; r < 2; ++r)
      async16(h1b + (size_t)(r0 + srow + r * 32) * 256 + kt * 64 + scol,
              &As2[(srow + r * 32) * 64 + scol]);
#pragma unroll
    for (int r = 0; r < 8; ++r)
      async16(w2t + (size_t)(srow + r * 32) * 256 + kt * 64 + scol,
              &Bs2[(srow + r * 32) * 64 + scol]);
    __syncthreads();
#pragma unroll
    for (int kk = 0; kk < 64; kk += 32) {
      v8bf a = *(const v8bf*)&As2[(wv * 16 + lm) * 64 + kk + quad * 8];
#pragma unroll
      for (int j = 0; j < 16; ++j) {
        v8bf b = *(const v8bf*)&Bs2[(j * 16 + lm) * 64 + kk + quad * 8];
        acc[j] = __builtin_amdgcn_mfma_f32_16x16x32_bf16(a, b, acc[j], 0, 0, 0);
      }
    }
  }
#pragma unroll
  for (int j = 0; j < 16; ++j) {
    int nn = j * 16 + lm;
    float bb = b2[nn];
#pragma unroll
    for (int r = 0; r < 4; ++r) {
      int row = wv * 16 + quad * 4 + r;
      Hs[row * 257 + nn] = fmaxf(acc[j][r] + bb, 0.f);
    }
  }
  __syncthreads();
  for (int o = tid; o < 384; o += 256) {
    int hd = o >> 6, r = o & 63;
    int grow = r0 + r;
    float d = 0.f;
    if (hd < 2) {
      for (int k = 0; k < 256; ++k) d += Hs[r * 257 + k] * wcls[k * 2 + hd];
      d += bcls[hd];
      if (grow < NROI) out[grow * 2 + hd] = d;
    } else {
      int h4 = hd - 2;
      for (int k = 0; k < 256; ++k) d += Hs[r * 257 + k] * wreg[k * 4 + h4];
      d += breg[h4];
      if (grow < NROI) out[4000 + grow * 4 + h4] = d;
    }
  }
}

extern "C" void kernel_launch(void* const* d_in, const int* in_sizes, int n_in,
                              void* d_out, int out_size, void* d_ws, size_t ws_size,
                              hipStream_t stream) {
  const float* features = (const float*)d_in[0];
  const int* rois = (const int*)d_in[1];
  const float* w1 = (const float*)d_in[2];
  const float* b1 = (const float*)d_in[3];
  const float* w2 = (const float*)d_in[4];
  const float* b2 = (const float*)d_in[5];
  const float* wcls = (const float*)d_in[6];
  const float* bcls = (const float*)d_in[7];
  const float* wreg = (const float*)d_in[8];
  const float* breg = (const float*)d_in[9];
  char* ws = (char*)d_ws;
  ushort* ft  = (ushort*)(ws + 0);          // 57,802,752 B
  ushort* w1t = (ushort*)(ws + 57802752);   //  6,422,528 B
  ushort* w2t = (ushort*)(ws + 64225280);   //    131,072 B
  ushort* rf  = (ushort*)(ws + 64356352);   // 51,380,224 B (2048 rows; rows
                                            // 2000+ are GEMM padding)
  // perm lives in rf's padding rows (read by gemm1 as harmless tiny bf16)
  int*    perm = (int*)(ws + 64356352 + (size_t)NROI * KDIM * 2);
  float*  P   = (float*)(ws + 115736576);   // 29,360,128 B
  ushort* h1b = (ushort*)(ws + 145096704);  //  1,048,576 B
  float* out = (float*)d_out;

  hipLaunchKernelGGL(k_transpose, dim3(HWSZ / 64), dim3(256), 0, stream,
                     features, (uint*)ft);
  hipLaunchKernelGGL(k_w1perm, dim3(392), dim3(256), 0, stream, w1, (uint*)w1t);
  hipLaunchKernelGGL(k_w2t, dim3(256), dim3(256), 0, stream, w2, w2t);
  hipLaunchKernelGGL(k_sort, dim3(1), dim3(256), 0, stream, rois, perm);
  hipLaunchKernelGGL(k_pool, dim3(NROI, 7), dim3(64), 0, stream, rois, perm,
                     (const uint4*)ft, (uint4*)rf);
  hipLaunchKernelGGL(k_gemm1, dim3(16, 2, SPLITK), dim3(256), 0, stream, rf, w1t, P);
  hipLaunchKernelGGL(k_reduce, dim3(1024), dim3(256), 0, stream, P, b1, (uint*)h1b);
  hipLaunchKernelGGL(k_gemm2, dim3(32), dim3(256), 0, stream, h1b, w2t, b2, wcls, bcls, wreg, breg, out);
}

// Round 8
// 353.142 us; speedup vs baseline: 1.1254x; 1.0026x over previous
//
#include <hip/hip_runtime.h>

typedef unsigned int uint;
typedef unsigned short ushort;
typedef __bf16 v8bf __attribute__((ext_vector_type(8)));
typedef float v4f __attribute__((ext_vector_type(4)));

#define CCH 256
#define HH 336
#define WW 336
#define HWSZ (HH*WW)
#define NROI 2000
#define KDIM 12544       // 49*256
#define MPAD 2048
#define SPLITK 14
#define KSP (KDIM/SPLITK)   // 896

__device__ __forceinline__ ushort bf16r(float f) {
  uint u = __float_as_uint(f);
  u += 0x7fffu + ((u >> 16) & 1u);   // RTNE
  return (ushort)(u >> 16);
}
__device__ __forceinline__ uint packbf(float a, float b) {
  return (uint)bf16r(a) | ((uint)bf16r(b) << 16);
}

typedef const __attribute__((address_space(1))) uint* gas_t;
typedef __attribute__((address_space(3))) uint* las_t;
__device__ __forceinline__ void async16(const void* g, void* l) {
  __builtin_amdgcn_global_load_lds((gas_t)g, (las_t)l, 16, 0, 0);
}

// features [256][336][336] fp32 -> ft [hw][c] bf16, LDS-tiled.
// Pad 134 (bank stride 6, gcd 2) -> phase-1 writes 2-way (free) vs 8-way at 132.
__global__ __launch_bounds__(256) void k_transpose(const float* __restrict__ f,
                                                   uint* __restrict__ ftu) {
  __shared__ uint T[64 * 134];
  int tid = threadIdx.x;
  int hw0 = blockIdx.x * 64;
  int hwl = tid & 63;
  int cq = tid >> 6;              // 0..3
  int hw = hw0 + hwl;
#pragma unroll 4
  for (int it = 0; it < 32; ++it) {
    int c = it * 8 + cq * 2;
    float a = f[(size_t)c * HWSZ + hw];
    float b = f[(size_t)(c + 1) * HWSZ + hw];
    T[hwl * 134 + it * 4 + cq] = packbf(a, b);
  }
  __syncthreads();
  int co = tid & 31, r = tid >> 5;   // 8 rows per iter
#pragma unroll
  for (int i = 0; i < 8; ++i) {
    int hwr = i * 8 + r;
    uint2 v0 = *(const uint2*)&T[hwr * 134 + co * 4];
    uint2 v1 = *(const uint2*)&T[hwr * 134 + co * 4 + 2];
    *(uint4*)(ftu + (size_t)(hw0 + hwr) * 128 + co * 4) =
        make_uint4(v0.x, v0.y, v1.x, v1.y);
  }
}

// w1 [12544][256] fp32 (k = c*49+bin) -> w1t bf16 [n][k'] with k' = bin*256+c
__global__ __launch_bounds__(256) void k_w1perm(const float* __restrict__ w1,
                                                uint* __restrict__ w1t_u) {
  int bin = blockIdx.x % 49;
  int c0 = (blockIdx.x / 49) * 32;
  __shared__ ushort T[32][258];
  int n = threadIdx.x;
  for (int i = 0; i < 32; ++i)
    T[i][n] = bf16r(w1[(size_t)((c0 + i) * 49 + bin) * 256 + n]);
  __syncthreads();
  int cc = threadIdx.x & 15;
  int nb = threadIdx.x >> 4;
  for (int rep = 0; rep < 16; ++rep) {
    int nn = rep * 16 + nb;
    uint v = (uint)T[2 * cc][nn] | ((uint)T[2 * cc + 1][nn] << 16);
    w1t_u[(size_t)nn * (KDIM / 2) + bin * 128 + c0 / 2 + cc] = v;
  }
}

// w2 [256][256] -> w2t bf16 [n][k]
__global__ __launch_bounds__(256) void k_w2t(const float* __restrict__ w2,
                                             ushort* __restrict__ w2t) {
  int n = blockIdx.x, k = threadIdx.x;
  w2t[n * 256 + k] = bf16r(w2[k * 256 + n]);
}

// Counting-sort ROIs by spatial tile (8x8 grid of 42px) -> perm.
__global__ __launch_bounds__(256) void k_sort(const int* __restrict__ rois,
                                              int* __restrict__ perm) {
  __shared__ int hist[64];
  __shared__ int keys[NROI];
  int tid = threadIdx.x;
  if (tid < 64) hist[tid] = 0;
  __syncthreads();
  for (int i = tid; i < NROI; i += 256) {
    int x1 = rois[i * 4 + 0], y1 = rois[i * 4 + 1];
    int x2 = rois[i * 4 + 2], y2 = rois[i * 4 + 3];
    int cx = (x1 + x2) >> 1, cy = (y1 + y2) >> 1;
    int k = (cy / 42) * 8 + (cx / 42);
    keys[i] = k;
    atomicAdd(&hist[k], 1);
  }
  __syncthreads();
  if (tid < 64) {                 // wave-0 exclusive prefix scan
    int v = hist[tid];
    int s = v;
#pragma unroll
    for (int d = 1; d < 64; d <<= 1) {
      int t = __shfl_up(s, d, 64);
      if (tid >= d) s += t;
    }
    hist[tid] = s - v;
  }
  __syncthreads();
  for (int i = tid; i < NROI; i += 256) {
    int pos = atomicAdd(&hist[keys[i]], 1);
    perm[pos] = i;
  }
}

// 1D grid 14000: L -> XCD = L&7 (round-robin dispatch), i = L>>3;
// slot = XCD*250 + i/7 (sorted ROI chunk per XCD), by = i%7.
// An ROI's 7 bin-rows are now dispatch-adjacent on one XCD -> no cross-slice
// L2 refetch (R6: FETCH 168 MB from by-major separation).
#define UNPK8(A, u) do {                                     \
  A[0] += __uint_as_float((u).x << 16);                      \
  A[1] += __uint_as_float((u).x & 0xffff0000u);              \
  A[2] += __uint_as_float((u).y << 16);                      \
  A[3] += __uint_as_float((u).y & 0xffff0000u);              \
  A[4] += __uint_as_float((u).z << 16);                      \
  A[5] += __uint_as_float((u).z & 0xffff0000u);              \
  A[6] += __uint_as_float((u).w << 16);                      \
  A[7] += __uint_as_float((u).w & 0xffff0000u);              \
} while (0)

__global__ __launch_bounds__(64) void k_pool(const int* __restrict__ rois,
                                             const int* __restrict__ perm,
                                             const uint4* __restrict__ ft4,
                                             uint4* __restrict__ rf4) {
  int L = blockIdx.x;
  int i = L >> 3;
  int slot = (L & 7) * 250 + i / 7;
  int by = i % 7;
  int n = perm[slot];
  int t = threadIdx.x;
  int co = t & 31, par = t >> 5;
  int x1 = rois[n * 4 + 0], y1 = rois[n * 4 + 1];
  int x2 = rois[n * 4 + 2], y2 = rois[n * 4 + 3];
  int Lw = x2 - x1 + 1, Lh = y2 - y1 + 1;
  int ylo = y1 + (by * Lh) / 7;
  int yhi = y1 + ((by + 1) * Lh + 6) / 7;
  int rh = yhi - ylo;
  uint ob = (uint)n * 1568 + (uint)by * 224 + co;
  for (int b = 0; b < 7; ++b) {
    int lo = x1 + (b * Lw) / 7;
    int hi = x1 + ((b + 1) * Lw + 6) / 7;
    float a[8], c[8];
#pragma unroll
    for (int j = 0; j < 8; ++j) { a[j] = 0.f; c[j] = 0.f; }
    for (int y = ylo; y < yhi; ++y) {
      const uint4* p = ft4 + (size_t)(y * WW + lo + par) * 32 + co;
      int x = lo + par;
      for (; x + 2 < hi; x += 4) {
        uint4 u0 = p[0], u1 = p[64];
        p += 128;
        UNPK8(a, u0);
        UNPK8(c, u1);
      }
      for (; x < hi; x += 2) {
        uint4 u = p[0];
        p += 64;
        UNPK8(a, u);
      }
    }
#pragma unroll
    for (int j = 0; j < 8; ++j) a[j] += c[j];
#pragma unroll
    for (int j = 0; j < 8; ++j) a[j] += __shfl_xor(a[j], 32, 64);
    if (t < 32) {
      float inv = 1.0f / (float)(rh * (hi - lo));
      uint4 o;
      o.x = packbf(a[0] * inv, a[1] * inv);
      o.y = packbf(a[2] * inv, a[3] * inv);
      o.z = packbf(a[4] * inv, a[5] * inv);
      o.w = packbf(a[6] * inv, a[7] * inv);
      rf4[ob + b * 32] = o;
    }
  }
}

// NT GEMM: A=rf [2048][12544], B=w1t [256][12544], 64x128 tiles, split-K.
// 896 blocks (3.5/CU, vs 1.75 at 128x128): more resident blocks to overlap
// the per-kt barrier drain. Wave: 32 rows x 64 cols (acc 2x4).
__global__ __launch_bounds__(256) void k_gemm1(const ushort* __restrict__ A,
                                               const ushort* __restrict__ B,
                                               float* __restrict__ P) {
  __shared__ ushort As[64 * 64];
  __shared__ ushort Bs[128 * 64];
  int m0 = blockIdx.x * 64;
  int n0 = blockIdx.y * 128;
  int ks = blockIdx.z;
  int k0 = ks * KSP;
  int tid = threadIdx.x;
  int lane = tid & 63, wv = tid >> 6;
  int wm = wv & 1, wn = wv >> 1;
  int lm = lane & 15, quad = lane >> 4;
  int srow = tid >> 3, scol = (tid & 7) * 8;
  v4f acc[2][4];
#pragma unroll
  for (int i = 0; i < 2; ++i)
#pragma unroll
    for (int j = 0; j < 4; ++j) acc[i][j] = (v4f){0.f, 0.f, 0.f, 0.f};
  const ushort* Ab = A + (size_t)(m0 + srow) * KDIM + k0 + scol;
  const ushort* Bb = B + (size_t)(n0 + srow) * KDIM + k0 + scol;
  for (int kt = 0; kt < KSP / 64; ++kt) {
    __syncthreads();
#pragma unroll
    for (int r = 0; r < 2; ++r)
      async16(Ab + (size_t)(r * 32) * KDIM + kt * 64, &As[(srow + r * 32) * 64 + scol]);
#pragma unroll
    for (int r = 0; r < 4; ++r)
      async16(Bb + (size_t)(r * 32) * KDIM + kt * 64, &Bs[(srow + r * 32) * 64 + scol]);
    __syncthreads();
#pragma unroll
    for (int kk = 0; kk < 64; kk += 32) {
      v8bf a[2], b[4];
#pragma unroll
      for (int i = 0; i < 2; ++i)
        a[i] = *(const v8bf*)&As[(wm * 32 + i * 16 + lm) * 64 + kk + quad * 8];
#pragma unroll
      for (int j = 0; j < 4; ++j)
        b[j] = *(const v8bf*)&Bs[(wn * 64 + j * 16 + lm) * 64 + kk + quad * 8];
#pragma unroll
      for (int i = 0; i < 2; ++i)
#pragma unroll
        for (int j = 0; j < 4; ++j)
          acc[i][j] = __builtin_amdgcn_mfma_f32_16x16x32_bf16(a[i], b[j], acc[i][j], 0, 0, 0);
    }
  }
  float* Pb = P + (size_t)ks * MPAD * 256;
#pragma unroll
  for (int i = 0; i < 2; ++i)
#pragma unroll
    for (int j = 0; j < 4; ++j) {
      int row = m0 + wm * 32 + i * 16 + quad * 4;
      int col = n0 + wn * 64 + j * 16 + lm;
#pragma unroll
      for (int r = 0; r < 4; ++r)
        Pb[(size_t)(row + r) * 256 + col] = acc[i][j][r];
    }
}

// sum split-K partials + bias + relu -> h1 bf16 [2048][256]
__global__ __launch_bounds__(256) void k_reduce(const float* __restrict__ P,
                                                const float* __restrict__ b1,
                                                uint* __restrict__ h1u) {
  int idx = blockIdx.x * 256 + threadIdx.x;  // < 2048*128
  int m = idx >> 7, np = idx & 127;
  const float2* Pp = (const float2*)P;
  float2 s = {0.f, 0.f};
#pragma unroll
  for (int ks = 0; ks < SPLITK; ++ks) {
    float2 v = Pp[(size_t)(ks * MPAD + m) * 128 + np];
    s.x += v.x; s.y += v.y;
  }
  s.x += b1[2 * np]; s.y += b1[2 * np + 1];
  s.x = fmaxf(s.x, 0.f); s.y = fmaxf(s.y, 0.f);
  h1u[idx] = packbf(s.x, s.y);
}

// GEMM2 (64 rows x full N=256, K=256) + fused cls/reg heads
__global__ __launch_bounds__(256) void k_gemm2(const ushort* __restrict__ h1b,
                                               const ushort* __restrict__ w2t,
                                               const float* __restrict__ b2,
                                               const float* __restrict__ wcls,
                                               const float* __restrict__ bcls,
                                               const float* __restrict__ wreg,
                                               const float* __restrict__ breg,
                                               float* __restrict__ out) {
  __shared__ ushort As2[64 * 64];
  __shared__ ushort Bs2[256 * 64];
  __shared__ float Hs[64 * 257];
  int tid = threadIdx.x;
  int r0 = blockIdx.x * 64;
  int lane = tid & 63, wv = tid >> 6;
  int lm = lane & 15, quad = lane >> 4;
  int srow = tid >> 3, scol = (tid & 7) * 8;
  v4f acc[16];
#pragma unroll
  for (int j = 0; j < 16; ++j) acc[j] = (v4f){0.f, 0.f, 0.f, 0.f};
  for (int kt = 0; kt < 4; ++kt) {
    __syncthreads();
#pragma unroll
    for (int r = 0; r < 2; ++r)
      async16(h1b + (size_t)(r0 + srow + r * 32) * 256 + kt * 64 + scol,
              &As2[(srow + r * 32) * 64 + scol]);
#pragma unroll
    for (int r = 0; r < 8; ++r)
      async16(w2t + (size_t)(srow + r * 32) * 256 + kt * 64 + scol,
              &Bs2[(srow + r * 32) * 64 + scol]);
    __syncthreads();
#pragma unroll
    for (int kk = 0; kk < 64; kk += 32) {
      v8bf a = *(const v8bf*)&As2[(wv * 16 + lm) * 64 + kk + quad * 8];
#pragma unroll
      for (int j = 0; j < 16; ++j) {
        v8bf b = *(const v8bf*)&Bs2[(j * 16 + lm) * 64 + kk + quad * 8];
        acc[j] = __builtin_amdgcn_mfma_f32_16x16x32_bf16(a, b, acc[j], 0, 0, 0);
      }
    }
  }
#pragma unroll
  for (int j = 0; j < 16; ++j) {
    int nn = j * 16 + lm;
    float bb = b2[nn];
#pragma unroll
    for (int r = 0; r < 4; ++r) {
      int row = wv * 16 + quad * 4 + r;
      Hs[row * 257 + nn] = fmaxf(acc[j][r] + bb, 0.f);
    }
  }
  __syncthreads();
  for (int o = tid; o < 384; o += 256) {
    int hd = o >> 6, r = o & 63;
    int grow = r0 + r;
    float d = 0.f;
    if (hd < 2) {
      for (int k = 0; k < 256; ++k) d += Hs[r * 257 + k] * wcls[k * 2 + hd];
      d += bcls[hd];
      if (grow < NROI) out[grow * 2 + hd] = d;
    } else {
      int h4 = hd - 2;
      for (int k = 0; k < 256; ++k) d += Hs[r * 257 + k] * wreg[k * 4 + h4];
      d += breg[h4];
      if (grow < NROI) out[4000 + grow * 4 + h4] = d;
    }
  }
}

extern "C" void kernel_launch(void* const* d_in, const int* in_sizes, int n_in,
                              void* d_out, int out_size, void* d_ws, size_t ws_size,
                              hipStream_t stream) {
  const float* features = (const float*)d_in[0];
  const int* rois = (const int*)d_in[1];
  const float* w1 = (const float*)d_in[2];
  const float* b1 = (const float*)d_in[3];
  const float* w2 = (const float*)d_in[4];
  const float* b2 = (const float*)d_in[5];
  const float* wcls = (const float*)d_in[6];
  const float* bcls = (const float*)d_in[7];
  const float* wreg = (const float*)d_in[8];
  const float* breg = (const float*)d_in[9];
  char* ws = (char*)d_ws;
  ushort* ft  = (ushort*)(ws + 0);          // 57,802,752 B
  ushort* w1t = (ushort*)(ws + 57802752);   //  6,422,528 B
  ushort* w2t = (ushort*)(ws + 64225280);   //    131,072 B
  ushort* rf  = (ushort*)(ws + 64356352);   // 51,380,224 B (2048 rows; rows
                                            // 2000+ are GEMM padding)
  // perm lives in rf's padding rows (read by gemm1 as harmless tiny bf16)
  int*    perm = (int*)(ws + 64356352 + (size_t)NROI * KDIM * 2);
  float*  P   = (float*)(ws + 115736576);   // 29,360,128 B
  ushort* h1b = (ushort*)(ws + 145096704);  //  1,048,576 B
  float* out = (float*)d_out;

  hipLaunchKernelGGL(k_transpose, dim3(HWSZ / 64), dim3(256), 0, stream,
                     features, (uint*)ft);
  hipLaunchKernelGGL(k_w1perm, dim3(392), dim3(256), 0, stream, w1, (uint*)w1t);
  hipLaunchKernelGGL(k_w2t, dim3(256), dim3(256), 0, stream, w2, w2t);
  hipLaunchKernelGGL(k_sort, dim3(1), dim3(256), 0, stream, rois, perm);
  hipLaunchKernelGGL(k_pool, dim3(NROI * 7), dim3(64), 0, stream, rois, perm,
                     (const uint4*)ft, (uint4*)rf);
  hipLaunchKernelGGL(k_gemm1, dim3(32, 2, SPLITK), dim3(256), 0, stream, rf, w1t, P);
  hipLaunchKernelGGL(k_reduce, dim3(1024), dim3(256), 0, stream, P, b1, (uint*)h1b);
  hipLaunchKernelGGL(k_gemm2, dim3(32), dim3(256), 0, stream, h1b, w2t, b2, wcls, bcls, wreg, breg, out);
}

// Round 9
// 351.261 us; speedup vs baseline: 1.1314x; 1.0054x over previous
//
#include <hip/hip_runtime.h>

typedef unsigned int uint;
typedef unsigned short ushort;
typedef __bf16 v8bf __attribute__((ext_vector_type(8)));
typedef float v4f __attribute__((ext_vector_type(4)));

#define CCH 256
#define HH 336
#define WW 336
#define HWSZ (HH*WW)
#define NROI 2000
#define KDIM 12544       // 49*256
#define MPAD 2048
#define SPLITK 14
#define KSP (KDIM/SPLITK)   // 896

__device__ __forceinline__ ushort bf16r(float f) {
  uint u = __float_as_uint(f);
  u += 0x7fffu + ((u >> 16) & 1u);   // RTNE
  return (ushort)(u >> 16);
}
__device__ __forceinline__ uint packbf(float a, float b) {
  return (uint)bf16r(a) | ((uint)bf16r(b) << 16);
}

typedef const __attribute__((address_space(1))) uint* gas_t;
typedef __attribute__((address_space(3))) uint* las_t;
__device__ __forceinline__ void async16(const void* g, void* l) {
  __builtin_amdgcn_global_load_lds((gas_t)g, (las_t)l, 16, 0, 0);
}

// features [256][336][336] fp32 -> ft [hw][c] bf16.
// v4: 128hw x 256ch tile; phase-1 float4/lane = 1KB/wave coalesced reads
// (was 256B/wave). LDS 128x134x4 = 68.6KB -> 2 blocks/CU. Phase-1 LDS b32
// writes are 8-way aliased but hide under the global-read pacing.
__global__ __launch_bounds__(256) void k_transpose(const float* __restrict__ f,
                                                   uint* __restrict__ ftu) {
  __shared__ uint T[128 * 134];
  int tid = threadIdx.x;
  int hw0 = blockIdx.x * 128;
  int hwq = tid & 31;             // hw-quad: hw = hw0 + hwq*4 .. +3
  int cp = tid >> 5;              // 0..7
#pragma unroll 2
  for (int j = 0; j < 16; ++j) {
    int cpair = j * 8 + cp;       // 0..127
    int c = cpair * 2;
    float4 fa = *(const float4*)&f[(size_t)c * HWSZ + hw0 + hwq * 4];
    float4 fb = *(const float4*)&f[(size_t)(c + 1) * HWSZ + hw0 + hwq * 4];
    T[(hwq * 4 + 0) * 134 + cpair] = packbf(fa.x, fb.x);
    T[(hwq * 4 + 1) * 134 + cpair] = packbf(fa.y, fb.y);
    T[(hwq * 4 + 2) * 134 + cpair] = packbf(fa.z, fb.z);
    T[(hwq * 4 + 3) * 134 + cpair] = packbf(fa.w, fb.w);
  }
  __syncthreads();
  int co = tid & 31, r = tid >> 5;   // 8 rows per iter
#pragma unroll 4
  for (int i = 0; i < 16; ++i) {
    int row = i * 8 + r;
    uint2 v0 = *(const uint2*)&T[row * 134 + co * 4];
    uint2 v1 = *(const uint2*)&T[row * 134 + co * 4 + 2];
    *(uint4*)(ftu + (size_t)(hw0 + row) * 128 + co * 4) =
        make_uint4(v0.x, v0.y, v1.x, v1.y);
  }
}

// Fused preprocessing: blocks 0..391 = w1perm, 392..423 = w2t, 424 = sort.
__global__ __launch_bounds__(256) void k_prep(const float* __restrict__ w1,
                                              uint* __restrict__ w1t_u,
                                              const float* __restrict__ w2,
                                              ushort* __restrict__ w2t,
                                              const int* __restrict__ rois,
                                              int* __restrict__ perm) {
  __shared__ ushort T[32][258];
  __shared__ int hist[64];
  __shared__ int keys[NROI];
  int tid = threadIdx.x;
  int b = blockIdx.x;
  if (b < 392) {
    // w1 [12544][256] fp32 (k=c*49+bin) -> w1t bf16 [n][k'], k'=bin*256+c
    int bin = b % 49;
    int c0 = (b / 49) * 32;
    int n = tid;
    for (int i = 0; i < 32; ++i)
      T[i][n] = bf16r(w1[(size_t)((c0 + i) * 49 + bin) * 256 + n]);
    __syncthreads();
    int cc = tid & 15;
    int nb = tid >> 4;
    for (int rep = 0; rep < 16; ++rep) {
      int nn = rep * 16 + nb;
      uint v = (uint)T[2 * cc][nn] | ((uint)T[2 * cc + 1][nn] << 16);
      w1t_u[(size_t)nn * (KDIM / 2) + bin * 128 + c0 / 2 + cc] = v;
    }
  } else if (b < 424) {
    // w2 [256][256] -> w2t bf16 [n][k]
    int n = (b - 392) * 8 + (tid >> 5);
    for (int kl = 0; kl < 8; ++kl) {
      int k = kl * 32 + (tid & 31);
      w2t[n * 256 + k] = bf16r(w2[k * 256 + n]);
    }
  } else {
    // counting-sort ROIs by spatial tile (8x8 grid of 42px) -> perm
    if (tid < 64) hist[tid] = 0;
    __syncthreads();
    for (int i = tid; i < NROI; i += 256) {
      int x1 = rois[i * 4 + 0], y1 = rois[i * 4 + 1];
      int x2 = rois[i * 4 + 2], y2 = rois[i * 4 + 3];
      int cx = (x1 + x2) >> 1, cy = (y1 + y2) >> 1;
      int k = (cy / 42) * 8 + (cx / 42);
      keys[i] = k;
      atomicAdd(&hist[k], 1);
    }
    __syncthreads();
    if (tid < 64) {               // wave-0 exclusive prefix scan
      int v = hist[tid];
      int s = v;
#pragma unroll
      for (int d = 1; d < 64; d <<= 1) {
        int t2 = __shfl_up(s, d, 64);
        if (tid >= d) s += t2;
      }
      hist[tid] = s - v;
    }
    __syncthreads();
    for (int i = tid; i < NROI; i += 256) {
      int pos = atomicAdd(&hist[keys[i]], 1);
      perm[pos] = i;
    }
  }
}

// 1D grid 14000: L -> XCD = L&7, i = L>>3; slot = XCD*250 + i/7, by = i%7.
// y x2 unroll: rows y (a/c accum) and y+1 (d/e accum) walked together with
// 2-stream x-unroll each -> 4 loads in flight.
// Pointer math: pixel = 32 uint4; x+=2 -> +64; row -> +336*32 = 10752.
#define UNPK8(A, u) do {                                     \
  A[0] += __uint_as_float((u).x << 16);                      \
  A[1] += __uint_as_float((u).x & 0xffff0000u);              \
  A[2] += __uint_as_float((u).y << 16);                      \
  A[3] += __uint_as_float((u).y & 0xffff0000u);              \
  A[4] += __uint_as_float((u).z << 16);                      \
  A[5] += __uint_as_float((u).z & 0xffff0000u);              \
  A[6] += __uint_as_float((u).w << 16);                      \
  A[7] += __uint_as_float((u).w & 0xffff0000u);              \
} while (0)

__global__ __launch_bounds__(64) void k_pool(const int* __restrict__ rois,
                                             const int* __restrict__ perm,
                                             const uint4* __restrict__ ft4,
                                             uint4* __restrict__ rf4) {
  int L = blockIdx.x;
  int i = L >> 3;
  int slot = (L & 7) * 250 + i / 7;
  int by = i % 7;
  int n = perm[slot];
  int t = threadIdx.x;
  int co = t & 31, par = t >> 5;
  int x1 = rois[n * 4 + 0], y1 = rois[n * 4 + 1];
  int x2 = rois[n * 4 + 2], y2 = rois[n * 4 + 3];
  int Lw = x2 - x1 + 1, Lh = y2 - y1 + 1;
  int ylo = y1 + (by * Lh) / 7;
  int yhi = y1 + ((by + 1) * Lh + 6) / 7;
  int rh = yhi - ylo;
  uint ob = (uint)n * 1568 + (uint)by * 224 + co;
  for (int b = 0; b < 7; ++b) {
    int lo = x1 + (b * Lw) / 7;
    int hi = x1 + ((b + 1) * Lw + 6) / 7;
    float a[8], c[8], d[8], e[8];
#pragma unroll
    for (int j = 0; j < 8; ++j) { a[j] = 0.f; c[j] = 0.f; d[j] = 0.f; e[j] = 0.f; }
    int y = ylo;
    for (; y + 1 < yhi; y += 2) {
      const uint4* p = ft4 + (size_t)(y * WW + lo + par) * 32 + co;
      const uint4* q = p + 336 * 32;
      int x = lo + par;
      for (; x + 2 < hi; x += 4) {
        uint4 u0 = p[0], u1 = p[64];
        uint4 v0 = q[0], v1 = q[64];
        p += 128; q += 128;
        UNPK8(a, u0);
        UNPK8(c, u1);
        UNPK8(d, v0);
        UNPK8(e, v1);
      }
      for (; x < hi; x += 2) {
        uint4 u = p[0], v = q[0];
        p += 64; q += 64;
        UNPK8(a, u);
        UNPK8(d, v);
      }
    }
    if (y < yhi) {                 // odd tail row
      const uint4* p = ft4 + (size_t)(y * WW + lo + par) * 32 + co;
      int x = lo + par;
      for (; x + 2 < hi; x += 4) {
        uint4 u0 = p[0], u1 = p[64];
        p += 128;
        UNPK8(a, u0);
        UNPK8(c, u1);
      }
      for (; x < hi; x += 2) {
        uint4 u = p[0];
        p += 64;
        UNPK8(a, u);
      }
    }
#pragma unroll
    for (int j = 0; j < 8; ++j) a[j] += c[j] + d[j] + e[j];
#pragma unroll
    for (int j = 0; j < 8; ++j) a[j] += __shfl_xor(a[j], 32, 64);
    if (t < 32) {
      float inv = 1.0f / (float)(rh * (hi - lo));
      uint4 o;
      o.x = packbf(a[0] * inv, a[1] * inv);
      o.y = packbf(a[2] * inv, a[3] * inv);
      o.z = packbf(a[4] * inv, a[5] * inv);
      o.w = packbf(a[6] * inv, a[7] * inv);
      rf4[ob + b * 32] = o;
    }
  }
}

// NT GEMM: A=rf [2048][12544], B=w1t [256][12544], 64x128 tiles, split-K.
__global__ __launch_bounds__(256) void k_gemm1(const ushort* __restrict__ A,
                                               const ushort* __restrict__ B,
                                               float* __restrict__ P) {
  __shared__ ushort As[64 * 64];
  __shared__ ushort Bs[128 * 64];
  int m0 = blockIdx.x * 64;
  int n0 = blockIdx.y * 128;
  int ks = blockIdx.z;
  int k0 = ks * KSP;
  int tid = threadIdx.x;
  int lane = tid & 63, wv = tid >> 6;
  int wm = wv & 1, wn = wv >> 1;
  int lm = lane & 15, quad = lane >> 4;
  int srow = tid >> 3, scol = (tid & 7) * 8;
  v4f acc[2][4];
#pragma unroll
  for (int i = 0; i < 2; ++i)
#pragma unroll
    for (int j = 0; j < 4; ++j) acc[i][j] = (v4f){0.f, 0.f, 0.f, 0.f};
  const ushort* Ab = A + (size_t)(m0 + srow) * KDIM + k0 + scol;
  const ushort* Bb = B + (size_t)(n0 + srow) * KDIM + k0 + scol;
  for (int kt = 0; kt < KSP / 64; ++kt) {
    __syncthreads();
#pragma unroll
    for (int r = 0; r < 2; ++r)
      async16(Ab + (size_t)(r * 32) * KDIM + kt * 64, &As[(srow + r * 32) * 64 + scol]);
#pragma unroll
    for (int r = 0; r < 4; ++r)
      async16(Bb + (size_t)(r * 32) * KDIM + kt * 64, &Bs[(srow + r * 32) * 64 + scol]);
    __syncthreads();
#pragma unroll
    for (int kk = 0; kk < 64; kk += 32) {
      v8bf a[2], b[4];
#pragma unroll
      for (int i = 0; i < 2; ++i)
        a[i] = *(const v8bf*)&As[(wm * 32 + i * 16 + lm) * 64 + kk + quad * 8];
#pragma unroll
      for (int j = 0; j < 4; ++j)
        b[j] = *(const v8bf*)&Bs[(wn * 64 + j * 16 + lm) * 64 + kk + quad * 8];
#pragma unroll
      for (int i = 0; i < 2; ++i)
#pragma unroll
        for (int j = 0; j < 4; ++j)
          acc[i][j] = __builtin_amdgcn_mfma_f32_16x16x32_bf16(a[i], b[j], acc[i][j], 0, 0, 0);
    }
  }
  float* Pb = P + (size_t)ks * MPAD * 256;
#pragma unroll
  for (int i = 0; i < 2; ++i)
#pragma unroll
    for (int j = 0; j < 4; ++j) {
      int row = m0 + wm * 32 + i * 16 + quad * 4;
      int col = n0 + wn * 64 + j * 16 + lm;
#pragma unroll
      for (int r = 0; r < 4; ++r)
        Pb[(size_t)(row + r) * 256 + col] = acc[i][j][r];
    }
}

// sum split-K partials + bias + relu -> h1 bf16 [2048][256]
__global__ __launch_bounds__(256) void k_reduce(const float* __restrict__ P,
                                                const float* __restrict__ b1,
                                                uint* __restrict__ h1u) {
  int idx = blockIdx.x * 256 + threadIdx.x;  // < 2048*128
  int m = idx >> 7, np = idx & 127;
  const float2* Pp = (const float2*)P;
  float2 s = {0.f, 0.f};
#pragma unroll
  for (int ks = 0; ks < SPLITK; ++ks) {
    float2 v = Pp[(size_t)(ks * MPAD + m) * 128 + np];
    s.x += v.x; s.y += v.y;
  }
  s.x += b1[2 * np]; s.y += b1[2 * np + 1];
  s.x = fmaxf(s.x, 0.f); s.y = fmaxf(s.y, 0.f);
  h1u[idx] = packbf(s.x, s.y);
}

// GEMM2 (64 rows x full N=256, K=256) + fused cls/reg heads
__global__ __launch_bounds__(256) void k_gemm2(const ushort* __restrict__ h1b,
                                               const ushort* __restrict__ w2t,
                                               const float* __restrict__ b2,
                                               const float* __restrict__ wcls,
                                               const float* __restrict__ bcls,
                                               const float* __restrict__ wreg,
                                               const float* __restrict__ breg,
                                               float* __restrict__ out) {
  __shared__ ushort As2[64 * 64];
  __shared__ ushort Bs2[256 * 64];
  __shared__ float Hs[64 * 257];
  int tid = threadIdx.x;
  int r0 = blockIdx.x * 64;
  int lane = tid & 63, wv = tid >> 6;
  int lm = lane & 15, quad = lane >> 4;
  int srow = tid >> 3, scol = (tid & 7) * 8;
  v4f acc[16];
#pragma unroll
  for (int j = 0; j < 16; ++j) acc[j] = (v4f){0.f, 0.f, 0.f, 0.f};
  for (int kt = 0; kt < 4; ++kt) {
    __syncthreads();
#pragma unroll
    for (int r = 0; r < 2; ++r)
      async16(h1b + (size_t)(r0 + srow + r * 32) * 256 + kt * 64 + scol,
              &As2[(srow + r * 32) * 64 + scol]);
#pragma unroll
    for (int r = 0; r < 8; ++r)
      async16(w2t + (size_t)(srow + r * 32) * 256 + kt * 64 + scol,
              &Bs2[(srow + r * 32) * 64 + scol]);
    __syncthreads();
#pragma unroll
    for (int kk = 0; kk < 64; kk += 32) {
      v8bf a = *(const v8bf*)&As2[(wv * 16 + lm) * 64 + kk + quad * 8];
#pragma unroll
      for (int j = 0; j < 16; ++j) {
        v8bf b = *(const v8bf*)&Bs2[(j * 16 + lm) * 64 + kk + quad * 8];
        acc[j] = __builtin_amdgcn_mfma_f32_16x16x32_bf16(a, b, acc[j], 0, 0, 0);
      }
    }
  }
#pragma unroll
  for (int j = 0; j < 16; ++j) {
    int nn = j * 16 + lm;
    float bb = b2[nn];
#pragma unroll
    for (int r = 0; r < 4; ++r) {
      int row = wv * 16 + quad * 4 + r;
      Hs[row * 257 + nn] = fmaxf(acc[j][r] + bb, 0.f);
    }
  }
  __syncthreads();
  for (int o = tid; o < 384; o += 256) {
    int hd = o >> 6, r = o & 63;
    int grow = r0 + r;
    float d = 0.f;
    if (hd < 2) {
      for (int k = 0; k < 256; ++k) d += Hs[r * 257 + k] * wcls[k * 2 + hd];
      d += bcls[hd];
      if (grow < NROI) out[grow * 2 + hd] = d;
    } else {
      int h4 = hd - 2;
      for (int k = 0; k < 256; ++k) d += Hs[r * 257 + k] * wreg[k * 4 + h4];
      d += breg[h4];
      if (grow < NROI) out[4000 + grow * 4 + h4] = d;
    }
  }
}

extern "C" void kernel_launch(void* const* d_in, const int* in_sizes, int n_in,
                              void* d_out, int out_size, void* d_ws, size_t ws_size,
                              hipStream_t stream) {
  const float* features = (const float*)d_in[0];
  const int* rois = (const int*)d_in[1];
  const float* w1 = (const float*)d_in[2];
  const float* b1 = (const float*)d_in[3];
  const float* w2 = (const float*)d_in[4];
  const float* b2 = (const float*)d_in[5];
  const float* wcls = (const float*)d_in[6];
  const float* bcls = (const float*)d_in[7];
  const float* wreg = (const float*)d_in[8];
  const float* breg = (const float*)d_in[9];
  char* ws = (char*)d_ws;
  ushort* ft  = (ushort*)(ws + 0);          // 57,802,752 B
  ushort* w1t = (ushort*)(ws + 57802752);   //  6,422,528 B
  ushort* w2t = (ushort*)(ws + 64225280);   //    131,072 B
  ushort* rf  = (ushort*)(ws + 64356352);   // 51,380,224 B (2048 rows; rows
                                            // 2000+ are GEMM padding)
  // perm lives in rf's padding rows (read by gemm1 as harmless tiny bf16)
  int*    perm = (int*)(ws + 64356352 + (size_t)NROI * KDIM * 2);
  float*  P   = (float*)(ws + 115736576);   // 29,360,128 B
  ushort* h1b = (ushort*)(ws + 145096704);  //  1,048,576 B
  float* out = (float*)d_out;

  hipLaunchKernelGGL(k_transpose, dim3(HWSZ / 128), dim3(256), 0, stream,
                     features, (uint*)ft);
  hipLaunchKernelGGL(k_prep, dim3(425), dim3(256), 0, stream,
                     w1, (uint*)w1t, w2, w2t, rois, perm);
  hipLaunchKernelGGL(k_pool, dim3(NROI * 7), dim3(64), 0, stream, rois, perm,
                     (const uint4*)ft, (uint4*)rf);
  hipLaunchKernelGGL(k_gemm1, dim3(32, 2, SPLITK), dim3(256), 0, stream, rf, w1t, P);
  hipLaunchKernelGGL(k_reduce, dim3(1024), dim3(256), 0, stream, P, b1, (uint*)h1b);
  hipLaunchKernelGGL(k_gemm2, dim3(32), dim3(256), 0, stream, h1b, w2t, b2, wcls, bcls, wreg, breg, out);
}